// Round 1
// 75.596 us; speedup vs baseline: 1.0145x; 1.0145x over previous
//
#include <hip/hip_runtime.h>

#define B_ 4
#define C_ 64
#define N_ 512
#define H_ 128   // hidden width = 2C

typedef float v2f __attribute__((ext_vector_type(2)));
typedef float v4f __attribute__((ext_vector_type(4)));

// ---------------------------------------------------------------------------
// Kernel 1: factorized first-layer projections.
//   L[b,i,h] = sum_c x[b,c,i] * W1[c,h]
//   R[b,j,h] = sum_c x[b,c,j] * W1[64+c,h] + b1[h]   (b1 folded into R)
// Output layout: [b][row][h], h contiguous (stride H_).
// Grid: 256 blocks = 2 halves x 4 b x 32 i-tiles(16 rows). Block 256 threads.
// Math in packed fp32 (v_pk_fma_f32): 4 pk-fma per cc per row-pair vs 8 scalar.
// ---------------------------------------------------------------------------
__global__ __launch_bounds__(256) void proj_kernel(
    const float* __restrict__ x, const float* __restrict__ W1,
    const float* __restrict__ b1, float* __restrict__ Lbuf,
    float* __restrict__ Rbuf)
{
    __shared__ float Wl[64 * 128];   // 32 KB: one half of W1 (64 rows x 128 cols)
    __shared__ float xs[16 * 68];    // x tile, transposed [ii][c], padded stride 68

    const int t    = threadIdx.x;
    const int half = blockIdx.x >> 7;          // 0 = L, 1 = R
    const int rem  = blockIdx.x & 127;
    const int b    = rem >> 5;
    const int i0   = (rem & 31) * 16;
    const int cbase = half * 64;

    // stage W half: rows cbase..cbase+63, all 128 cols = 2048 float4, coalesced
    const float4* W14 = (const float4*)W1;
    float4* Wl4 = (float4*)Wl;
    #pragma unroll
    for (int k = 0; k < 8; ++k)
        Wl4[t + k * 256] = W14[cbase * 32 + t + k * 256];

    // stage x tile: xs[ii*68 + c] = x[b, c, i0+ii]
    #pragma unroll
    for (int k = 0; k < 4; ++k) {
        int idx = t + k * 256;                  // 0..1023
        int c = idx >> 4, ii = idx & 15;
        xs[ii * 68 + c] = x[b * (C_ * N_) + c * N_ + i0 + ii];
    }
    __syncthreads();

    const int hq  = t & 31;           // column quad (4 h's)
    const int il  = (t >> 5) * 2;     // local row base (2 rows per thread)
    const int col = hq * 4;

    v2f a0l = {0.f, 0.f}, a0h = {0.f, 0.f};
    if (half) {
        float4 bv = *(const float4*)(b1 + col);
        a0l = {bv.x, bv.y};
        a0h = {bv.z, bv.w};
    }
    v2f a1l = a0l, a1h = a0h;

    const v4f* Wlv = (const v4f*)Wl;
    #pragma unroll
    for (int c = 0; c < 64; c += 4) {
        float4 xv0 = *(float4*)(xs + il * 68 + c);
        float4 xv1 = *(float4*)(xs + (il + 1) * 68 + c);
        const float* x0p = (const float*)&xv0;
        const float* x1p = (const float*)&xv1;
        #pragma unroll
        for (int cc = 0; cc < 4; ++cc) {
            v4f wv = Wlv[(c + cc) * 32 + hq];
            v2f wl = wv.xy, wh = wv.zw;
            v2f xb0 = {x0p[cc], x0p[cc]};
            v2f xb1 = {x1p[cc], x1p[cc]};
            a0l = __builtin_elementwise_fma(wl, xb0, a0l);
            a0h = __builtin_elementwise_fma(wh, xb0, a0h);
            a1l = __builtin_elementwise_fma(wl, xb1, a1l);
            a1h = __builtin_elementwise_fma(wh, xb1, a1h);
        }
    }

    float* buf = half ? Rbuf : Lbuf;
    float* o = buf + b * (N_ * H_) + (i0 + il) * H_ + col;
    *(float4*)o        = make_float4(a0l.x, a0l.y, a0h.x, a0h.y);
    *(float4*)(o + H_) = make_float4(a1l.x, a1l.y, a1h.x, a1h.y);
}

// ---------------------------------------------------------------------------
// Kernel 2: pairwise scores, 32x32 tiles.
//   out[b,i,j] = (j > i) ? sum_h relu(L[i,h] + R[j,h]) * W2[h] + b2 : 0
// Grid: 1024 blocks, 256 threads. Blocks 0..543 = work tiles (upper triangle
// incl. diagonal, decoded directly so they dispatch first and balance across
// CUs); blocks 544..1023 = strictly-lower zero tiles (cheap, trail).
// LDS 32 KB (2 x 32row x 32quad v4f). XOR swizzle col' = hc ^ (row>>2):
// 1 VALU vs 2 for rotate, same 16-bank x 2-way (free) conflict profile, and
// the row+1 read folds into ds_read offset:512.
// Math in packed fp32: per hc per thread 8x{pk_add, 2x v_max, pk_fma} = ~32
// VALU vs 48 scalar. 8 split v2f accumulators for FMA-chain ILP.
// ---------------------------------------------------------------------------
__global__ __launch_bounds__(256) void pair_kernel(
    const float* __restrict__ Lbuf, const float* __restrict__ Rbuf,
    const float* __restrict__ W2, const float* __restrict__ b2,
    float* __restrict__ out)
{
    __shared__ v4f Lt4[32 * 32];   // 16 KB
    __shared__ v4f Rt4[32 * 32];   // 16 KB

    const int t = threadIdx.x;
    int b, it, jt;
    {
        int bid = blockIdx.x;
        if (bid >= 544) {
            // strictly-lower tile: zero-fill (row it has it tiles, jt in [0,it))
            int z = bid - 544;
            b = z & 3;
            int k = z >> 2;                    // 0..119
            it = 1;
            while (k >= it) { k -= it; ++it; }
            jt = k;
            float* outb = out + b * (N_ * N_);
            const int r = t >> 3, cq = t & 7;  // 32 rows x 8 float4-cols
            *(float4*)(outb + (it * 32 + r) * N_ + jt * 32 + cq * 4) =
                make_float4(0.f, 0.f, 0.f, 0.f);
            return;
        }
        // work tile: row it has 16-it tiles, jt in [it,16)
        b = bid & 3;
        int k = bid >> 2;                      // 0..135
        it = 0;
        while (k >= 16 - it) { k -= 16 - it; ++it; }
        jt = it + k;
    }
    const int ti0 = it * 32, tj0 = jt * 32;
    float* outb = out + b * (N_ * N_);

    // stage L and R tiles: 1024 v4f each, 4 per thread per tile, XOR-swizzled
    const float* Lsrc = Lbuf + b * (N_ * H_) + ti0 * H_;
    const float* Rsrc = Rbuf + b * (N_ * H_) + tj0 * H_;
    #pragma unroll
    for (int kk = 0; kk < 4; ++kk) {
        int idx = t + kk * 256;                // 0..1023
        int row = idx >> 5, hc = idx & 31;
        int sc = hc ^ (row >> 2);
        Lt4[row * 32 + sc] = *(const v4f*)(Lsrc + row * H_ + hc * 4);
        Rt4[row * 32 + sc] = *(const v4f*)(Rsrc + row * H_ + hc * 4);
    }
    __syncthreads();

    const int w    = t >> 6;
    const int lane = t & 63;
    const int til  = (w >> 1) * 16 + (lane >> 3) * 2;  // local i base (2 rows)
    const int tjl  = (w & 1) * 16 + (lane & 7) * 2;    // local j base (2 cols)
    const int rotL = til >> 2;                         // (til+1)>>2 == til>>2 (til even)
    const int rotR = tjl >> 2;

    const v4f* Lp  = Lt4 + til * 32;
    const v4f* Rp  = Rt4 + tjl * 32;
    const v4f* W24 = (const v4f*)W2;

    v2f c00l = {0.f, 0.f}, c00h = {0.f, 0.f};
    v2f c01l = {0.f, 0.f}, c01h = {0.f, 0.f};
    v2f c10l = {0.f, 0.f}, c10h = {0.f, 0.f};
    v2f c11l = {0.f, 0.f}, c11h = {0.f, 0.f};

    #pragma unroll 8
    for (int hc = 0; hc < 32; ++hc) {
        const int oL = hc ^ rotL;
        const int oR = hc ^ rotR;
        v4f L0 = Lp[oL];
        v4f L1 = Lp[32 + oL];                  // same addr reg, offset:512
        v4f R0 = Rp[oR];
        v4f R1 = Rp[32 + oR];
        v4f wv = W24[hc];                      // wave-uniform -> scalar load
        v2f wl = wv.xy, wh = wv.zw;
        const v2f z2 = {0.f, 0.f};
        v2f s;
        s = __builtin_elementwise_max(L0.xy + R0.xy, z2);
        c00l = __builtin_elementwise_fma(s, wl, c00l);
        s = __builtin_elementwise_max(L0.zw + R0.zw, z2);
        c00h = __builtin_elementwise_fma(s, wh, c00h);
        s = __builtin_elementwise_max(L0.xy + R1.xy, z2);
        c01l = __builtin_elementwise_fma(s, wl, c01l);
        s = __builtin_elementwise_max(L0.zw + R1.zw, z2);
        c01h = __builtin_elementwise_fma(s, wh, c01h);
        s = __builtin_elementwise_max(L1.xy + R0.xy, z2);
        c10l = __builtin_elementwise_fma(s, wl, c10l);
        s = __builtin_elementwise_max(L1.zw + R0.zw, z2);
        c10h = __builtin_elementwise_fma(s, wh, c10h);
        s = __builtin_elementwise_max(L1.xy + R1.xy, z2);
        c11l = __builtin_elementwise_fma(s, wl, c11l);
        s = __builtin_elementwise_max(L1.zw + R1.zw, z2);
        c11h = __builtin_elementwise_fma(s, wh, c11h);
    }

    const float bias2 = b2[0];
    float a00 = (c00l.x + c00l.y) + (c00h.x + c00h.y);
    float a01 = (c01l.x + c01l.y) + (c01h.x + c01h.y);
    float a10 = (c10l.x + c10l.y) + (c10h.x + c10h.y);
    float a11 = (c11l.x + c11l.y) + (c11h.x + c11h.y);

    const int gi0 = ti0 + til, gj0 = tj0 + tjl;
    float2 v0, v1;
    v0.x = (gj0     > gi0    ) ? (a00 + bias2) : 0.f;
    v0.y = (gj0 + 1 > gi0    ) ? (a01 + bias2) : 0.f;
    v1.x = (gj0     > gi0 + 1) ? (a10 + bias2) : 0.f;
    v1.y = (gj0 + 1 > gi0 + 1) ? (a11 + bias2) : 0.f;
    *(float2*)(outb + gi0 * N_ + gj0) = v0;
    *(float2*)(outb + (gi0 + 1) * N_ + gj0) = v1;
}

extern "C" void kernel_launch(void* const* d_in, const int* in_sizes, int n_in,
                              void* d_out, int out_size, void* d_ws, size_t ws_size,
                              hipStream_t stream)
{
    const float* x  = (const float*)d_in[0];
    const float* W1 = (const float*)d_in[1];
    const float* b1 = (const float*)d_in[2];
    const float* W2 = (const float*)d_in[3];
    const float* b2 = (const float*)d_in[4];
    float* out  = (float*)d_out;
    float* Lbuf = (float*)d_ws;                 // B*N*H floats = 1 MB
    float* Rbuf = Lbuf + B_ * N_ * H_;          // +1 MB

    proj_kernel<<<256, 256, 0, stream>>>(x, W1, b1, Lbuf, Rbuf);
    pair_kernel<<<B_ * 256, 256, 0, stream>>>(Lbuf, Rbuf, W2, b2, out);
}